// Round 1
// baseline (388.948 us; speedup 1.0000x reference)
//
#include <hip/hip_runtime.h>
#include <hip/hip_bf16.h>

#define D_ 768
#define E_ 8
#define H_ 3072
#define N_TOK 4096
#define BM 64
#define BN 64
#define BK 32
#define PADL 40  // halfs per LDS row (32 + 8 pad, keeps 16B alignment)

typedef _Float16 f16;
typedef f16 f16x8 __attribute__((ext_vector_type(8)));
typedef float f32x4 __attribute__((ext_vector_type(4)));

// ---------------- x -> fp16 ----------------
__global__ __launch_bounds__(256) void cvt_x(const float* __restrict__ x,
                                             f16* __restrict__ xh) {
    size_t i = ((size_t)blockIdx.x * 256 + threadIdx.x) * 8;
    float4 a = *(const float4*)(x + i);
    float4 b = *(const float4*)(x + i + 4);
    f16x8 o;
    o[0] = (f16)a.x; o[1] = (f16)a.y; o[2] = (f16)a.z; o[3] = (f16)a.w;
    o[4] = (f16)b.x; o[5] = (f16)b.y; o[6] = (f16)b.z; o[7] = (f16)b.w;
    *(f16x8*)(xh + i) = o;
}

// ---------------- router: logits, top-2, softmax, grouping ----------------
__global__ __launch_bounds__(256) void router(const float* __restrict__ x,
                                              const float* __restrict__ gw,
                                              const float* __restrict__ gb,
                                              int* __restrict__ counts,
                                              int* __restrict__ list,
                                              float* __restrict__ wslot) {
    int wv = threadIdx.x >> 6;
    int lane = threadIdx.x & 63;
    int tok = blockIdx.x * 4 + wv;
    const float* xr = x + (size_t)tok * D_;
    float acc[E_];
#pragma unroll
    for (int e = 0; e < E_; e++) acc[e] = 0.f;
    for (int d = lane; d < D_; d += 64) {
        float v = xr[d];
        const float* g = gw + d * E_;
#pragma unroll
        for (int e = 0; e < E_; e++) acc[e] += v * g[e];
    }
#pragma unroll
    for (int e = 0; e < E_; e++) {
#pragma unroll
        for (int off = 32; off; off >>= 1) acc[e] += __shfl_xor(acc[e], off, 64);
    }
    if (lane == 0) {
        float v0 = -3.4e38f, v1 = -3.4e38f;
        int i0 = 0, i1 = 0;
#pragma unroll
        for (int e = 0; e < E_; e++) {
            float l = acc[e] + gb[e];
            if (l > v0) { v1 = v0; i1 = i0; v0 = l; i0 = e; }
            else if (l > v1) { v1 = l; i1 = e; }
        }
        float p1 = expf(v1 - v0);
        float s = 1.f + p1;
        float w0 = 1.f / s;
        float w1 = p1 / s;
        int p0 = atomicAdd(&counts[i0], 1);
        list[i0 * N_TOK + p0] = tok * 2;
        int p1p = atomicAdd(&counts[i1], 1);
        list[i1 * N_TOK + p1p] = tok * 2 + 1;
        wslot[tok * 2] = w0;
        wslot[tok * 2 + 1] = w1;
    }
}

// ---------------- GEMM1: h = gelu(x @ w1 + b1), grouped by expert ----------------
__global__ __launch_bounds__(256) void gemm1(const f16* __restrict__ xh,
                                             const float* __restrict__ w1,
                                             const float* __restrict__ b1,
                                             const int* __restrict__ counts,
                                             const int* __restrict__ list,
                                             f16* __restrict__ hbuf) {
    int e = blockIdx.z;
    int cnt = counts[e];
    int rb = blockIdx.y * BM;
    if (rb >= cnt) return;
    int cb = blockIdx.x * BN;

    __shared__ f16 Alds[BM][PADL];
    __shared__ f16 Blds[BN][PADL];
    __shared__ int ids[BM];

    int tid = threadIdx.x;
    if (tid < BM) {
        int idx = rb + tid;
        ids[tid] = (idx < cnt) ? list[e * N_TOK + idx] : -1;
    }
    __syncthreads();

    // A staging: thread -> (row, 8-half chunk)
    int ar = tid >> 2;
    int ak = (tid & 3) * 8;
    int aid = ids[ar];
    const f16* arow = (aid >= 0) ? (xh + (size_t)(aid >> 1) * D_) : (const f16*)0;
    // B staging: thread -> (col, 8 k values down a column)
    int bcol = tid & 63;
    int bk = (tid >> 6) * 8;
    const float* wbase = w1 + (size_t)e * D_ * H_ + (cb + bcol);

    int wv = tid >> 6;
    int lane = tid & 63;
    int wr = (wv >> 1) * 32, wc = (wv & 1) * 32;
    int fr = lane & 15, fk = (lane >> 4) * 8;

    f32x4 acc[2][2] = {};

    for (int kk = 0; kk < D_; kk += BK) {
        f16x8 av = {};
        if (arow) av = *(const f16x8*)(arow + kk + ak);
        *(f16x8*)&Alds[ar][ak] = av;
        f16 bv[8];
        const float* wp = wbase + (size_t)(kk + bk) * H_;
#pragma unroll
        for (int i = 0; i < 8; i++) bv[i] = (f16)wp[(size_t)i * H_];
        *(f16x8*)&Blds[bcol][bk] = *(f16x8*)bv;
        __syncthreads();

        f16x8 a0 = *(const f16x8*)&Alds[wr + fr][fk];
        f16x8 a1 = *(const f16x8*)&Alds[wr + 16 + fr][fk];
        f16x8 b0 = *(const f16x8*)&Blds[wc + fr][fk];
        f16x8 b1f = *(const f16x8*)&Blds[wc + 16 + fr][fk];
        acc[0][0] = __builtin_amdgcn_mfma_f32_16x16x32_f16(a0, b0, acc[0][0], 0, 0, 0);
        acc[0][1] = __builtin_amdgcn_mfma_f32_16x16x32_f16(a0, b1f, acc[0][1], 0, 0, 0);
        acc[1][0] = __builtin_amdgcn_mfma_f32_16x16x32_f16(a1, b0, acc[1][0], 0, 0, 0);
        acc[1][1] = __builtin_amdgcn_mfma_f32_16x16x32_f16(a1, b1f, acc[1][1], 0, 0, 0);
        __syncthreads();
    }

#pragma unroll
    for (int fn = 0; fn < 2; fn++) {
        int colg = cb + wc + fn * 16 + fr;
        float bias = b1[e * H_ + colg];
#pragma unroll
        for (int fm = 0; fm < 2; fm++) {
#pragma unroll
            for (int r = 0; r < 4; r++) {
                int rloc = wr + fm * 16 + (lane >> 4) * 4 + r;
                int id = ids[rloc];
                if (id >= 0) {
                    float v = acc[fm][fn][r] + bias;
                    v = 0.5f * v * (1.f + erff(v * 0.70710678f));
                    hbuf[(size_t)id * H_ + colg] = (f16)v;
                }
            }
        }
    }
}

// ---------------- GEMM2: y = h @ w2 + b2, weighted scatter-add ----------------
__global__ __launch_bounds__(256) void gemm2(const f16* __restrict__ hbuf,
                                             const float* __restrict__ w2,
                                             const float* __restrict__ b2,
                                             const int* __restrict__ counts,
                                             const int* __restrict__ list,
                                             const float* __restrict__ wslot,
                                             float* __restrict__ out) {
    int e = blockIdx.z;
    int cnt = counts[e];
    int rb = blockIdx.y * BM;
    if (rb >= cnt) return;
    int cb = blockIdx.x * BN;

    __shared__ f16 Alds[BM][PADL];
    __shared__ f16 Blds[BN][PADL];
    __shared__ int ids[BM];

    int tid = threadIdx.x;
    if (tid < BM) {
        int idx = rb + tid;
        ids[tid] = (idx < cnt) ? list[e * N_TOK + idx] : -1;
    }
    __syncthreads();

    int ar = tid >> 2;
    int ak = (tid & 3) * 8;
    int aid = ids[ar];
    const f16* arow = (aid >= 0) ? (hbuf + (size_t)aid * H_) : (const f16*)0;
    int bcol = tid & 63;
    int bk = (tid >> 6) * 8;
    const float* wbase = w2 + (size_t)e * H_ * D_ + (cb + bcol);

    int wv = tid >> 6;
    int lane = tid & 63;
    int wr = (wv >> 1) * 32, wc = (wv & 1) * 32;
    int fr = lane & 15, fk = (lane >> 4) * 8;

    f32x4 acc[2][2] = {};

    for (int kk = 0; kk < H_; kk += BK) {
        f16x8 av = {};
        if (arow) av = *(const f16x8*)(arow + kk + ak);
        *(f16x8*)&Alds[ar][ak] = av;
        f16 bv[8];
        const float* wp = wbase + (size_t)(kk + bk) * D_;
#pragma unroll
        for (int i = 0; i < 8; i++) bv[i] = (f16)wp[(size_t)i * D_];
        *(f16x8*)&Blds[bcol][bk] = *(f16x8*)bv;
        __syncthreads();

        f16x8 a0 = *(const f16x8*)&Alds[wr + fr][fk];
        f16x8 a1 = *(const f16x8*)&Alds[wr + 16 + fr][fk];
        f16x8 b0 = *(const f16x8*)&Blds[wc + fr][fk];
        f16x8 b1f = *(const f16x8*)&Blds[wc + 16 + fr][fk];
        acc[0][0] = __builtin_amdgcn_mfma_f32_16x16x32_f16(a0, b0, acc[0][0], 0, 0, 0);
        acc[0][1] = __builtin_amdgcn_mfma_f32_16x16x32_f16(a0, b1f, acc[0][1], 0, 0, 0);
        acc[1][0] = __builtin_amdgcn_mfma_f32_16x16x32_f16(a1, b0, acc[1][0], 0, 0, 0);
        acc[1][1] = __builtin_amdgcn_mfma_f32_16x16x32_f16(a1, b1f, acc[1][1], 0, 0, 0);
        __syncthreads();
    }

#pragma unroll
    for (int fn = 0; fn < 2; fn++) {
        int colg = cb + wc + fn * 16 + fr;
        float bias = b2[e * D_ + colg];
#pragma unroll
        for (int fm = 0; fm < 2; fm++) {
#pragma unroll
            for (int r = 0; r < 4; r++) {
                int rloc = wr + fm * 16 + (lane >> 4) * 4 + r;
                int id = ids[rloc];
                if (id >= 0) {
                    float w = wslot[id];
                    float v = (acc[fm][fn][r] + bias) * w;
                    atomicAdd(&out[(size_t)(id >> 1) * D_ + colg], v);
                }
            }
        }
    }
}

extern "C" void kernel_launch(void* const* d_in, const int* in_sizes, int n_in,
                              void* d_out, int out_size, void* d_ws, size_t ws_size,
                              hipStream_t stream) {
    const float* x = (const float*)d_in[0];
    const float* gate_w = (const float*)d_in[1];
    const float* gate_b = (const float*)d_in[2];
    const float* w1 = (const float*)d_in[3];
    const float* b1 = (const float*)d_in[4];
    const float* w2 = (const float*)d_in[5];
    const float* b2 = (const float*)d_in[6];
    float* out = (float*)d_out;

    char* ws = (char*)d_ws;
    int* counts = (int*)ws;                                  // 32 B
    int* list = (int*)(ws + 256);                            // 8*4096*4 = 131072
    float* wslot = (float*)(ws + 256 + 131072);              // 8192*4 = 32768
    f16* xh = (f16*)(ws + 164096);                           // 4096*768*2 = 6291456
    f16* hbuf = (f16*)(ws + 164096 + 6291456);               // 8192*3072*2 = 50331648

    hipMemsetAsync(counts, 0, 8 * sizeof(int), stream);
    hipMemsetAsync(out, 0, (size_t)out_size * sizeof(float), stream);

    cvt_x<<<1536, 256, 0, stream>>>(x, xh);
    router<<<1024, 256, 0, stream>>>(x, gate_w, gate_b, counts, list, wslot);
    gemm1<<<dim3(H_ / BN, N_TOK / BM, E_), 256, 0, stream>>>(xh, w1, b1, counts, list, hbuf);
    gemm2<<<dim3(D_ / BN, N_TOK / BM, E_), 256, 0, stream>>>(hbuf, w2, b2, counts, list, wslot, out);
}